// Round 1
// baseline (2068.641 us; speedup 1.0000x reference)
//
#include <hip/hip_runtime.h>
#include <math.h>

#define N_NODES 50000
#define N_EDGES 800000
#define E_TOT   (N_EDGES + N_NODES)
#define NEG_SLOPE 0.2f

// ---- monotonic float<->uint key for atomicMax on f32 ----
__device__ __forceinline__ unsigned f2key(float f) {
    unsigned b = __float_as_uint(f);
    return (b & 0x80000000u) ? ~b : (b | 0x80000000u);
}
__device__ __forceinline__ float key2f(unsigned k) {
    unsigned b = (k & 0x80000000u) ? (k & 0x7FFFFFFFu) : ~k;
    return __uint_as_float(b);
}

// ---- dual GEMM: XL = X @ Wl, XR = X @ Wr.  X:[n,K], W:[K,NOUT] ----
// block = 2*NOUT threads; each block handles ROWS rows, X rows staged in LDS.
template<int K, int NOUT, int ROWS>
__global__ void dual_linear(const float* __restrict__ X,
                            const float* __restrict__ Wl,
                            const float* __restrict__ Wr,
                            float* __restrict__ XL,
                            float* __restrict__ XR,
                            int n) {
    __shared__ float xs[ROWS][K];
    int r0 = blockIdx.x * ROWS;
    for (int i = threadIdx.x; i < ROWS * K; i += blockDim.x) {
        int r = i / K, k = i % K;
        int row = r0 + r;
        xs[r][k] = (row < n) ? X[(size_t)row * K + k] : 0.f;
    }
    __syncthreads();
    int t = threadIdx.x;
    const float* W = (t < NOUT) ? Wl : Wr;
    float* O       = (t < NOUT) ? XL : XR;
    int col        = (t < NOUT) ? t  : t - NOUT;
    float acc[ROWS];
#pragma unroll
    for (int r = 0; r < ROWS; ++r) acc[r] = 0.f;
    for (int k = 0; k < K; ++k) {
        float w = W[k * NOUT + col];
#pragma unroll
        for (int r = 0; r < ROWS; ++r) acc[r] += xs[r][k] * w;  // xs broadcast: conflict-free
    }
#pragma unroll
    for (int r = 0; r < ROWS; ++r) {
        int row = r0 + r;
        if (row < n) O[(size_t)row * NOUT + col] = acc[r];
    }
}

// ---- edge scoring: logit[e,h] = att[h] . leaky_relu(xl[src]+xr[dst]); amax via atomicMax ----
template<int H, int C>
__global__ void edge_score(const int* __restrict__ esrc, const int* __restrict__ edst,
                           const float* __restrict__ XL, const float* __restrict__ XR,
                           const float* __restrict__ att,
                           float* __restrict__ logit, unsigned* __restrict__ amax) {
    long long tid = (long long)blockIdx.x * blockDim.x + threadIdx.x;
    if (tid >= (long long)E_TOT * H) return;
    int e = (int)(tid / H), h = (int)(tid % H);
    int s, d;
    if (e < N_EDGES) { s = esrc[e]; d = edst[e]; } else { s = d = e - N_EDGES; }
    const float4* xl = (const float4*)(XL + ((size_t)s * H + h) * C);
    const float4* xr = (const float4*)(XR + ((size_t)d * H + h) * C);
    const float4* at = (const float4*)(att + (size_t)h * C);
    float acc = 0.f;
#pragma unroll
    for (int i = 0; i < C / 4; ++i) {
        float4 a = xl[i], b = xr[i], w = at[i];
        float v;
        v = a.x + b.x; acc += w.x * (v > 0.f ? v : NEG_SLOPE * v);
        v = a.y + b.y; acc += w.y * (v > 0.f ? v : NEG_SLOPE * v);
        v = a.z + b.z; acc += w.z * (v > 0.f ? v : NEG_SLOPE * v);
        v = a.w + b.w; acc += w.w * (v > 0.f ? v : NEG_SLOPE * v);
    }
    logit[tid] = acc;
    atomicMax(amax + (size_t)d * H + h, f2key(acc));
}

// ---- denom[dst,h] += exp(logit - amax[dst,h]) ----
template<int H>
__global__ void edge_expsum(const int* __restrict__ edst,
                            const float* __restrict__ logit,
                            const unsigned* __restrict__ amax,
                            float* __restrict__ denom) {
    long long tid = (long long)blockIdx.x * blockDim.x + threadIdx.x;
    if (tid >= (long long)E_TOT * H) return;
    int e = (int)(tid / H), h = (int)(tid % H);
    int d = (e < N_EDGES) ? edst[e] : e - N_EDGES;
    float m = key2f(amax[(size_t)d * H + h]);
    atomicAdd(denom + (size_t)d * H + h, __expf(logit[tid] - m));
}

// ---- out[dst, c] += xl[src, c] * alpha(e, h=c/C) ----
template<int H, int C>
__global__ void edge_aggregate(const int* __restrict__ esrc, const int* __restrict__ edst,
                               const float* __restrict__ XL,
                               const float* __restrict__ logit,
                               const unsigned* __restrict__ amax,
                               const float* __restrict__ denom,
                               float* __restrict__ out) {
    constexpr int HOUT = H * C;
    long long tid = (long long)blockIdx.x * blockDim.x + threadIdx.x;
    if (tid >= (long long)E_TOT * HOUT) return;
    int e = (int)(tid / HOUT), c = (int)(tid % HOUT);
    int h = c / C;
    int s, d;
    if (e < N_EDGES) { s = esrc[e]; d = edst[e]; } else { s = d = e - N_EDGES; }
    float m = key2f(amax[(size_t)d * H + h]);
    float alpha = __expf(logit[(size_t)e * H + h] - m) / denom[(size_t)d * H + h];
    atomicAdd(out + (size_t)d * HOUT + c, XL[(size_t)s * HOUT + c] * alpha);
}

// ---- out = elu(out + bias), in place ----
template<int HOUT>
__global__ void bias_elu(float* __restrict__ out, const float* __restrict__ bias) {
    long long tid = (long long)blockIdx.x * blockDim.x + threadIdx.x;
    if (tid >= (long long)N_NODES * HOUT) return;
    int c = (int)(tid % HOUT);
    float v = out[tid] + bias[c];
    out[tid] = v > 0.f ? v : expm1f(v);
}

static inline int cdiv_ll(long long a, int b) { return (int)((a + b - 1) / b); }

extern "C" void kernel_launch(void* const* d_in, const int* in_sizes, int n_in,
                              void* d_out, int out_size, void* d_ws, size_t ws_size,
                              hipStream_t stream) {
    const float* x    = (const float*)d_in[0];
    const int*   ei   = (const int*)d_in[1];     // [2, E] int32
    const int*   esrc = ei;
    const int*   edst = ei + N_EDGES;
    const float* W1l = (const float*)d_in[2];
    const float* W1r = (const float*)d_in[3];
    const float* att1= (const float*)d_in[4];
    const float* b1  = (const float*)d_in[5];
    const float* W2l = (const float*)d_in[6];
    const float* W2r = (const float*)d_in[7];
    const float* att2= (const float*)d_in[8];
    const float* b2  = (const float*)d_in[9];
    const float* W3l = (const float*)d_in[10];
    const float* W3r = (const float*)d_in[11];
    const float* att3= (const float*)d_in[12];
    const float* b3  = (const float*)d_in[13];
    float* out = (float*)d_out;

    // workspace layout (floats)
    float* XL = (float*)d_ws;                       // 50000*128
    float* XR = XL + (size_t)N_NODES * 128;         // 50000*128
    float* Hb = XR + (size_t)N_NODES * 128;         // 50000*128
    float* LG = Hb + (size_t)N_NODES * 128;         // E_TOT*2
    unsigned* AM = (unsigned*)(LG + (size_t)E_TOT * 2);  // 50000*2
    float* DEN = (float*)(AM + (size_t)N_NODES * 2);     // 50000*2

    const int TB = 256;

    // ================= layer 1: in 128 -> H=2, C=64 =================
    dual_linear<128, 128, 16><<<(N_NODES + 15) / 16, 256, 0, stream>>>(x, W1l, W1r, XL, XR, N_NODES);
    hipMemsetAsync(Hb, 0, (size_t)N_NODES * 128 * 4, stream);
    hipMemsetAsync(AM, 0, (size_t)N_NODES * 2 * 4, stream);
    hipMemsetAsync(DEN, 0, (size_t)N_NODES * 2 * 4, stream);
    edge_score<2, 64><<<cdiv_ll((long long)E_TOT * 2, TB), TB, 0, stream>>>(esrc, edst, XL, XR, att1, LG, AM);
    edge_expsum<2><<<cdiv_ll((long long)E_TOT * 2, TB), TB, 0, stream>>>(edst, LG, AM, DEN);
    edge_aggregate<2, 64><<<cdiv_ll((long long)E_TOT * 128, TB), TB, 0, stream>>>(esrc, edst, XL, LG, AM, DEN, Hb);
    bias_elu<128><<<cdiv_ll((long long)N_NODES * 128, TB), TB, 0, stream>>>(Hb, b1);

    // ================= layer 2: in 128 -> H=2, C=64 =================
    dual_linear<128, 128, 16><<<(N_NODES + 15) / 16, 256, 0, stream>>>(Hb, W2l, W2r, XL, XR, N_NODES);
    hipMemsetAsync(Hb, 0, (size_t)N_NODES * 128 * 4, stream);
    hipMemsetAsync(AM, 0, (size_t)N_NODES * 2 * 4, stream);
    hipMemsetAsync(DEN, 0, (size_t)N_NODES * 2 * 4, stream);
    edge_score<2, 64><<<cdiv_ll((long long)E_TOT * 2, TB), TB, 0, stream>>>(esrc, edst, XL, XR, att2, LG, AM);
    edge_expsum<2><<<cdiv_ll((long long)E_TOT * 2, TB), TB, 0, stream>>>(edst, LG, AM, DEN);
    edge_aggregate<2, 64><<<cdiv_ll((long long)E_TOT * 128, TB), TB, 0, stream>>>(esrc, edst, XL, LG, AM, DEN, Hb);
    bias_elu<128><<<cdiv_ll((long long)N_NODES * 128, TB), TB, 0, stream>>>(Hb, b2);

    // ================= layer 3: in 128 -> H=1, C=64 =================
    dual_linear<128, 64, 16><<<(N_NODES + 15) / 16, 128, 0, stream>>>(Hb, W3l, W3r, XL, XR, N_NODES);
    hipMemsetAsync(out, 0, (size_t)N_NODES * 64 * 4, stream);
    hipMemsetAsync(AM, 0, (size_t)N_NODES * 1 * 4, stream);
    hipMemsetAsync(DEN, 0, (size_t)N_NODES * 1 * 4, stream);
    edge_score<1, 64><<<cdiv_ll((long long)E_TOT * 1, TB), TB, 0, stream>>>(esrc, edst, XL, XR, att3, LG, AM);
    edge_expsum<1><<<cdiv_ll((long long)E_TOT * 1, TB), TB, 0, stream>>>(edst, LG, AM, DEN);
    edge_aggregate<1, 64><<<cdiv_ll((long long)E_TOT * 64, TB), TB, 0, stream>>>(esrc, edst, XL, LG, AM, DEN, out);
    bias_elu<64><<<cdiv_ll((long long)N_NODES * 64, TB), TB, 0, stream>>>(out, b3);
}

// Round 2
// 684.740 us; speedup vs baseline: 3.0211x; 3.0211x over previous
//
#include <hip/hip_runtime.h>
#include <math.h>

#define N_NODES 50000
#define N_EDGES 800000
#define NEG_SLOPE 0.2f

static inline int cdiv(long long a, int b) { return (int)((a + b - 1) / b); }

// ================= CSR build =================
__global__ void hist_deg(const int* __restrict__ edst, int* __restrict__ deg) {
    int e = blockIdx.x * blockDim.x + threadIdx.x;
    if (e < N_EDGES) atomicAdd(&deg[edst[e]], 1);
}

#define SCAN_T 1024
#define SCAN_V 4
// single-block exclusive scan of deg[0..N_NODES) -> off[0..N_NODES], cur = copy of off
__global__ void scan_offsets(const int* __restrict__ deg, int* __restrict__ off,
                             int* __restrict__ cur) {
    __shared__ int buf[SCAN_T];
    __shared__ int s_carry;
    if (threadIdx.x == 0) s_carry = 0;
    __syncthreads();
    for (int base = 0; base < N_NODES; base += SCAN_T * SCAN_V) {
        int idx0 = base + threadIdx.x * SCAN_V;
        int v[SCAN_V];
        int sum = 0;
#pragma unroll
        for (int u = 0; u < SCAN_V; ++u) {
            int i = idx0 + u;
            v[u] = (i < N_NODES) ? deg[i] : 0;
            sum += v[u];
        }
        buf[threadIdx.x] = sum;
        __syncthreads();
        for (int s = 1; s < SCAN_T; s <<= 1) {
            int t = (threadIdx.x >= s) ? buf[threadIdx.x - s] : 0;
            __syncthreads();
            buf[threadIdx.x] += t;
            __syncthreads();
        }
        int excl = buf[threadIdx.x] - sum;  // exclusive prefix within chunk
        int run = s_carry + excl;           // read carry BEFORE it's updated (sync below)
#pragma unroll
        for (int u = 0; u < SCAN_V; ++u) {
            int i = idx0 + u;
            if (i < N_NODES) { off[i] = run; cur[i] = run; }
            run += v[u];
        }
        __syncthreads();
        if (threadIdx.x == SCAN_T - 1) s_carry += buf[SCAN_T - 1];
        __syncthreads();
    }
    if (threadIdx.x == 0) off[N_NODES] = s_carry;
}

__global__ void scatter_csr(const int* __restrict__ esrc, const int* __restrict__ edst,
                            int* __restrict__ cur, int* __restrict__ csr) {
    int e = blockIdx.x * blockDim.x + threadIdx.x;
    if (e < N_EDGES) {
        int d = edst[e];
        int p = atomicAdd(&cur[d], 1);
        csr[p] = esrc[e];
    }
}

// ================= dual GEMM: XL = X @ Wl, XR = X @ Wr =================
template<int K, int NOUT, int ROWS>
__global__ void dual_linear(const float* __restrict__ X,
                            const float* __restrict__ Wl,
                            const float* __restrict__ Wr,
                            float* __restrict__ XL,
                            float* __restrict__ XR,
                            int n) {
    __shared__ float xs[ROWS][K];
    int r0 = blockIdx.x * ROWS;
    for (int i = threadIdx.x; i < ROWS * K; i += blockDim.x) {
        int r = i / K, k = i % K;
        int row = r0 + r;
        xs[r][k] = (row < n) ? X[(size_t)row * K + k] : 0.f;
    }
    __syncthreads();
    int t = threadIdx.x;
    const float* W = (t < NOUT) ? Wl : Wr;
    float* O       = (t < NOUT) ? XL : XR;
    int col        = (t < NOUT) ? t  : t - NOUT;
    float acc[ROWS];
#pragma unroll
    for (int r = 0; r < ROWS; ++r) acc[r] = 0.f;
    for (int k = 0; k < K; ++k) {
        float w = W[k * NOUT + col];
#pragma unroll
        for (int r = 0; r < ROWS; ++r) acc[r] += xs[r][k] * w;  // xs broadcast: conflict-free
    }
#pragma unroll
    for (int r = 0; r < ROWS; ++r) {
        int row = r0 + r;
        if (row < n) O[(size_t)row * NOUT + col] = acc[r];
    }
}

// ================= fused GATv2: score + online softmax + aggregate + bias + elu =================
// One wave per destination node. Lane layout: head h = lane/LPH, VEC channels per lane.
template<int H, int C>
__global__ void fused_gat(const float* __restrict__ XL, const float* __restrict__ XR,
                          const int* __restrict__ off, const int* __restrict__ csr,
                          const float* __restrict__ att, const float* __restrict__ bias,
                          float* __restrict__ out) {
    constexpr int HOUT = H * C;
    constexpr int VEC  = HOUT / 64;   // channels per lane (2 for H=2,C=64; 1 for H=1,C=64)
    constexpr int LPH  = 64 / H;      // lanes per head
    int wave = threadIdx.x >> 6;
    int lane = threadIdx.x & 63;
    int node = blockIdx.x * (blockDim.x >> 6) + wave;
    if (node >= N_NODES) return;
    int lh = lane % LPH;
    int cbase = (lane / LPH) * C + lh * VEC;  // channel offset within HOUT

    float atv[VEC], xrv[VEC];
#pragma unroll
    for (int u = 0; u < VEC; ++u) atv[u] = att[cbase + u];
    const float* xr_row = XR + (size_t)node * HOUT + cbase;
#pragma unroll
    for (int u = 0; u < VEC; ++u) xrv[u] = xr_row[u];

    float acc[VEC], m, denom;
    // --- self loop first: initializes online-softmax state (no -inf handling) ---
    {
        const float* ar = XL + (size_t)node * HOUT + cbase;
        float a[VEC];
#pragma unroll
        for (int u = 0; u < VEC; ++u) a[u] = ar[u];
        float partial = 0.f;
#pragma unroll
        for (int u = 0; u < VEC; ++u) {
            float v = a[u] + xrv[u];
            partial += atv[u] * (v > 0.f ? v : NEG_SLOPE * v);
        }
#pragma unroll
        for (int o = 1; o < LPH; o <<= 1) partial += __shfl_xor(partial, o);
        m = partial;
        denom = 1.f;
#pragma unroll
        for (int u = 0; u < VEC; ++u) acc[u] = a[u];
    }
    // --- incoming real edges, software-pipelined gather ---
    int k = off[node], kend = off[node + 1];
    float an[VEC];
    if (k < kend) {
        int jn = csr[k];
        const float* ar = XL + (size_t)jn * HOUT + cbase;
#pragma unroll
        for (int u = 0; u < VEC; ++u) an[u] = ar[u];
    }
    while (k < kend) {
        float a[VEC];
#pragma unroll
        for (int u = 0; u < VEC; ++u) a[u] = an[u];
        ++k;
        if (k < kend) {
            int jn = csr[k];
            const float* ar = XL + (size_t)jn * HOUT + cbase;
#pragma unroll
            for (int u = 0; u < VEC; ++u) an[u] = ar[u];
        }
        float partial = 0.f;
#pragma unroll
        for (int u = 0; u < VEC; ++u) {
            float v = a[u] + xrv[u];
            partial += atv[u] * (v > 0.f ? v : NEG_SLOPE * v);
        }
#pragma unroll
        for (int o = 1; o < LPH; o <<= 1) partial += __shfl_xor(partial, o);
        float s = partial;
        float mn = fmaxf(m, s);
        float scale = __expf(m - mn);
        float f = __expf(s - mn);
        denom = denom * scale + f;
#pragma unroll
        for (int u = 0; u < VEC; ++u) acc[u] = acc[u] * scale + a[u] * f;
        m = mn;
    }
    // --- epilogue: normalize, bias, elu ---
    float* orow = out + (size_t)node * HOUT + cbase;
#pragma unroll
    for (int u = 0; u < VEC; ++u) {
        float r = acc[u] / denom + bias[cbase + u];
        orow[u] = r > 0.f ? r : expm1f(r);
    }
}

extern "C" void kernel_launch(void* const* d_in, const int* in_sizes, int n_in,
                              void* d_out, int out_size, void* d_ws, size_t ws_size,
                              hipStream_t stream) {
    const float* x    = (const float*)d_in[0];
    const int*   ei   = (const int*)d_in[1];  // [2, E] int32
    const int*   esrc = ei;
    const int*   edst = ei + N_EDGES;
    const float* W1l = (const float*)d_in[2];
    const float* W1r = (const float*)d_in[3];
    const float* att1= (const float*)d_in[4];
    const float* b1  = (const float*)d_in[5];
    const float* W2l = (const float*)d_in[6];
    const float* W2r = (const float*)d_in[7];
    const float* att2= (const float*)d_in[8];
    const float* b2  = (const float*)d_in[9];
    const float* W3l = (const float*)d_in[10];
    const float* W3r = (const float*)d_in[11];
    const float* att3= (const float*)d_in[12];
    const float* b3  = (const float*)d_in[13];
    float* out = (float*)d_out;

    // workspace layout
    float* XL  = (float*)d_ws;                       // 50000*128
    float* XR  = XL + (size_t)N_NODES * 128;         // 50000*128
    float* Hb  = XR + (size_t)N_NODES * 128;         // 50000*128
    int* deg   = (int*)(Hb + (size_t)N_NODES * 128); // 50000
    int* off   = deg + N_NODES;                      // 50001
    int* cur   = off + N_NODES + 1;                  // 50000
    int* csr   = cur + N_NODES;                      // 800000

    const int TB = 256;

    // ---- CSR build (per call; ws is re-poisoned every timed launch) ----
    hipMemsetAsync(deg, 0, (size_t)N_NODES * 4, stream);
    hist_deg<<<cdiv(N_EDGES, TB), TB, 0, stream>>>(edst, deg);
    scan_offsets<<<1, SCAN_T, 0, stream>>>(deg, off, cur);
    scatter_csr<<<cdiv(N_EDGES, TB), TB, 0, stream>>>(esrc, edst, cur, csr);

    const int WPB = 4;  // waves (nodes) per block
    int gat_grid = cdiv(N_NODES, WPB);

    // ---- layer 1 ----
    dual_linear<128, 128, 16><<<cdiv(N_NODES, 16), 256, 0, stream>>>(x, W1l, W1r, XL, XR, N_NODES);
    fused_gat<2, 64><<<gat_grid, WPB * 64, 0, stream>>>(XL, XR, off, csr, att1, b1, Hb);
    // ---- layer 2 ----
    dual_linear<128, 128, 16><<<cdiv(N_NODES, 16), 256, 0, stream>>>(Hb, W2l, W2r, XL, XR, N_NODES);
    fused_gat<2, 64><<<gat_grid, WPB * 64, 0, stream>>>(XL, XR, off, csr, att2, b2, Hb);
    // ---- layer 3 ----
    dual_linear<128, 64, 16><<<cdiv(N_NODES, 16), 128, 0, stream>>>(Hb, W3l, W3r, XL, XR, N_NODES);
    fused_gat<1, 64><<<gat_grid, WPB * 64, 0, stream>>>(XL, XR, off, csr, att3, b3, out);
}

// Round 3
// 432.936 us; speedup vs baseline: 4.7782x; 1.5816x over previous
//
#include <hip/hip_runtime.h>
#include <hip/hip_fp16.h>
#include <math.h>

#define N_NODES 50000
#define N_EDGES 800000
#define NEG_SLOPE 0.2f

typedef _Float16 v8h __attribute__((ext_vector_type(8)));
typedef _Float16 half4 __attribute__((ext_vector_type(4)));
typedef float f32x4 __attribute__((ext_vector_type(4)));

static inline int cdiv(long long a, int b) { return (int)((a + b - 1) / b); }

// ================= casts / packing =================
__global__ void cast_to_half(const float* __restrict__ in, _Float16* __restrict__ out, int n4) {
    int i = blockIdx.x * blockDim.x + threadIdx.x;
    if (i < n4) {
        float4 v = ((const float4*)in)[i];
        half4 h;
        h[0] = (_Float16)v.x; h[1] = (_Float16)v.y; h[2] = (_Float16)v.z; h[3] = (_Float16)v.w;
        ((half4*)out)[i] = h;
    }
}

__global__ void pack_weights(const float* __restrict__ W1l, const float* __restrict__ W1r,
                             const float* __restrict__ W2l, const float* __restrict__ W2r,
                             const float* __restrict__ W3l, const float* __restrict__ W3r,
                             _Float16* __restrict__ Wt1, _Float16* __restrict__ Wt2,
                             _Float16* __restrict__ Wt3) {
    int id = blockIdx.x * blockDim.x + threadIdx.x;
    if (id < 32768) {                       // Wt1: [256][128]
        int n = id >> 7, k = id & 127;
        Wt1[id] = (_Float16)(n < 128 ? W1l[k * 128 + n] : W1r[k * 128 + n - 128]);
    } else if (id < 65536) {                // Wt2: [256][128]
        int j = id - 32768; int n = j >> 7, k = j & 127;
        Wt2[j] = (_Float16)(n < 128 ? W2l[k * 128 + n] : W2r[k * 128 + n - 128]);
    } else if (id < 81920) {                // Wt3: [128][128]
        int j = id - 65536; int n = j >> 7, k = j & 127;
        Wt3[j] = (_Float16)(n < 64 ? W3l[k * 64 + n] : W3r[k * 64 + n - 64]);
    }
}

// ================= CSR build =================
__global__ void hist_deg(const int* __restrict__ edst, int* __restrict__ deg) {
    int e = blockIdx.x * blockDim.x + threadIdx.x;
    if (e < N_EDGES) atomicAdd(&deg[edst[e]], 1);
}

#define SC_B 1024
#define SC_V 4
#define SC_CHUNK (SC_B * SC_V)                       // 4096
#define SC_NB ((N_NODES + SC_CHUNK - 1) / SC_CHUNK)  // 13

__global__ void scan_block_sums(const int* __restrict__ deg, int* __restrict__ bsum) {
    __shared__ int red[SC_B];
    int base = blockIdx.x * SC_CHUNK + threadIdx.x * SC_V;
    int s = 0;
#pragma unroll
    for (int u = 0; u < SC_V; ++u) {
        int i = base + u;
        if (i < N_NODES) s += deg[i];
    }
    red[threadIdx.x] = s;
    __syncthreads();
    for (int st = SC_B / 2; st > 0; st >>= 1) {
        if (threadIdx.x < st) red[threadIdx.x] += red[threadIdx.x + st];
        __syncthreads();
    }
    if (threadIdx.x == 0) bsum[blockIdx.x] = red[0];
}

__global__ void scan_bsum(const int* __restrict__ bsum, int* __restrict__ bbase) {
    if (threadIdx.x == 0) {
        int r = 0;
        for (int b = 0; b < SC_NB; ++b) { bbase[b] = r; r += bsum[b]; }
    }
}

__global__ void scan_apply(const int* __restrict__ deg, const int* __restrict__ bbase,
                           int* __restrict__ off, int* __restrict__ cur) {
    __shared__ int buf[SC_B];
    int idx0 = blockIdx.x * SC_CHUNK + threadIdx.x * SC_V;
    int v[SC_V];
    int sum = 0;
#pragma unroll
    for (int u = 0; u < SC_V; ++u) {
        int i = idx0 + u;
        v[u] = (i < N_NODES) ? deg[i] : 0;
        sum += v[u];
    }
    buf[threadIdx.x] = sum;
    __syncthreads();
    for (int st = 1; st < SC_B; st <<= 1) {
        int t = (threadIdx.x >= st) ? buf[threadIdx.x - st] : 0;
        __syncthreads();
        buf[threadIdx.x] += t;
        __syncthreads();
    }
    int run = bbase[blockIdx.x] + buf[threadIdx.x] - sum;  // exclusive prefix
#pragma unroll
    for (int u = 0; u < SC_V; ++u) {
        int i = idx0 + u;
        if (i < N_NODES) { off[i] = run; cur[i] = run; }
        run += v[u];
    }
    if (blockIdx.x == 0 && threadIdx.x == 0) off[N_NODES] = N_EDGES;
}

__global__ void scatter_csr(const int* __restrict__ esrc, const int* __restrict__ edst,
                            int* __restrict__ cur, int* __restrict__ csr) {
    int e = blockIdx.x * blockDim.x + threadIdx.x;
    if (e < N_EDGES) {
        int d = edst[e];
        int p = atomicAdd(&cur[d], 1);
        csr[p] = esrc[e];
    }
}

// ================= MFMA GEMM: C[M][NT] = A[M][128] @ Bt[NT][128]^T, f16 in, f32 acc =================
template<int NT>
__global__ __launch_bounds__(256, 2) void gemm_xlr(const _Float16* __restrict__ A,
                                                   const _Float16* __restrict__ Bt,
                                                   _Float16* __restrict__ C) {
    int w = threadIdx.x >> 6, lane = threadIdx.x & 63;
    int m0 = blockIdx.x * 128 + (w & 1) * 64;
    int n0 = blockIdx.y * 128 + (w >> 1) * 64;
    int q = lane >> 4, li = lane & 15;
    f32x4 acc[4][4] = {};
    const _Float16* Ap = A + (size_t)(m0 + li) * 128 + q * 8;   // A[m][k=q*8+j]
    const _Float16* Bp = Bt + (size_t)(n0 + li) * 128 + q * 8;  // B[n][k=q*8+j]
#pragma unroll
    for (int kt = 0; kt < 4; ++kt) {
        v8h af[4], bf[4];
#pragma unroll
        for (int a = 0; a < 4; ++a) af[a] = *(const v8h*)(Ap + (size_t)(16 * a) * 128 + kt * 32);
#pragma unroll
        for (int b = 0; b < 4; ++b) bf[b] = *(const v8h*)(Bp + (size_t)(16 * b) * 128 + kt * 32);
#pragma unroll
        for (int a = 0; a < 4; ++a)
#pragma unroll
            for (int b = 0; b < 4; ++b)
                acc[a][b] = __builtin_amdgcn_mfma_f32_16x16x32_f16(af[a], bf[b], acc[a][b], 0, 0, 0);
    }
    // C/D layout: col = lane&15, row = q*4 + reg
#pragma unroll
    for (int a = 0; a < 4; ++a) {
        int mb = m0 + 16 * a + q * 4;
#pragma unroll
        for (int r = 0; r < 4; ++r) {
            int m = mb + r;
            if (m < N_NODES) {
#pragma unroll
                for (int b = 0; b < 4; ++b) {
                    int n = n0 + 16 * b + li;
                    C[(size_t)m * NT + n] = (_Float16)acc[a][b][r];
                }
            }
        }
    }
}

// ================= fused GATv2: score + softmax (no max-sub) + aggregate + bias + elu =================
template<int HOUT, typename OUT_T>
__global__ __launch_bounds__(256, 4) void fused_gat(
    const _Float16* __restrict__ XLR,   // [N][2*HOUT] = [xl | xr]
    const int* __restrict__ off, const int* __restrict__ csr,
    const float* __restrict__ att, const float* __restrict__ bias,
    OUT_T* __restrict__ out) {          // [N][HOUT]
    constexpr int VEC = 4;
    constexpr int LPE = HOUT / VEC;     // lanes per edge (32 or 16)
    constexpr int EPW = 64 / LPE;       // edges per wave (2 or 4)
    constexpr int ST = 2 * HOUT;
    int wave = threadIdx.x >> 6, lane = threadIdx.x & 63;
    int node = blockIdx.x * (blockDim.x >> 6) + wave;
    if (node >= N_NODES) return;
    int g = lane / LPE;
    int lg = lane % LPE;
    int cb = lg * VEC;

    float at0 = att[cb], at1 = att[cb + 1], at2 = att[cb + 2], at3 = att[cb + 3];
    half4 xrh = *(const half4*)(XLR + (size_t)node * ST + HOUT + cb);
    float xr0 = (float)xrh[0], xr1 = (float)xrh[1], xr2 = (float)xrh[2], xr3 = (float)xrh[3];

    int eoff = off[node];
    int P = off[node + 1] - eoff + 1;   // position 0 = self-loop, 1..deg = csr edges
    float denom = 0.f, acc0 = 0.f, acc1 = 0.f, acc2 = 0.f, acc3 = 0.f;

    for (int p = g; p < P; p += EPW) {
        int idx = eoff + (p > 0 ? p - 1 : 0);
        idx = min(idx, N_EDGES - 1);
        int src = (p == 0) ? node : csr[idx];
        half4 ah = *(const half4*)(XLR + (size_t)src * ST + cb);
        float a0 = (float)ah[0], a1 = (float)ah[1], a2 = (float)ah[2], a3 = (float)ah[3];
        float v0 = a0 + xr0, v1 = a1 + xr1, v2 = a2 + xr2, v3 = a3 + xr3;
        float s = at0 * fmaxf(v0, NEG_SLOPE * v0) + at1 * fmaxf(v1, NEG_SLOPE * v1)
                + at2 * fmaxf(v2, NEG_SLOPE * v2) + at3 * fmaxf(v3, NEG_SLOPE * v3);
        s += __shfl_xor(s, 1); s += __shfl_xor(s, 2); s += __shfl_xor(s, 4); s += __shfl_xor(s, 8);
        float f = __expf(s);
        denom += f;
        acc0 += a0 * f; acc1 += a1 * f; acc2 += a2 * f; acc3 += a3 * f;
    }
#pragma unroll
    for (int o = LPE; o < 64; o <<= 1) {
        acc0 += __shfl_xor(acc0, o); acc1 += __shfl_xor(acc1, o);
        acc2 += __shfl_xor(acc2, o); acc3 += __shfl_xor(acc3, o);
        denom += __shfl_xor(denom, o);
    }
    if (lane < LPE) {
        float inv = 1.f / denom;
        float r0 = acc0 * inv + bias[cb];
        float r1 = acc1 * inv + bias[cb + 1];
        float r2 = acc2 * inv + bias[cb + 2];
        float r3 = acc3 * inv + bias[cb + 3];
        r0 = r0 > 0.f ? r0 : expm1f(r0);
        r1 = r1 > 0.f ? r1 : expm1f(r1);
        r2 = r2 > 0.f ? r2 : expm1f(r2);
        r3 = r3 > 0.f ? r3 : expm1f(r3);
        OUT_T* orow = out + (size_t)node * HOUT + cb;
        orow[0] = (OUT_T)r0; orow[1] = (OUT_T)r1; orow[2] = (OUT_T)r2; orow[3] = (OUT_T)r3;
    }
}

extern "C" void kernel_launch(void* const* d_in, const int* in_sizes, int n_in,
                              void* d_out, int out_size, void* d_ws, size_t ws_size,
                              hipStream_t stream) {
    const float* x    = (const float*)d_in[0];
    const int*   ei   = (const int*)d_in[1];
    const int*   esrc = ei;
    const int*   edst = ei + N_EDGES;
    const float* W1l = (const float*)d_in[2];
    const float* W1r = (const float*)d_in[3];
    const float* att1= (const float*)d_in[4];
    const float* b1  = (const float*)d_in[5];
    const float* W2l = (const float*)d_in[6];
    const float* W2r = (const float*)d_in[7];
    const float* att2= (const float*)d_in[8];
    const float* b2  = (const float*)d_in[9];
    const float* W3l = (const float*)d_in[10];
    const float* W3r = (const float*)d_in[11];
    const float* att3= (const float*)d_in[12];
    const float* b3  = (const float*)d_in[13];
    float* out = (float*)d_out;

    // ---- workspace layout ----
    _Float16* XLR = (_Float16*)d_ws;                    // 50000*256
    _Float16* Xb  = XLR + (size_t)N_NODES * 256;        // 50000*128 (GEMM tail OOB reads land in Hb: safe)
    _Float16* Hb  = Xb + (size_t)N_NODES * 128;         // 50000*128 (tail OOB reads land in Wt: safe)
    _Float16* Wt1 = Hb + (size_t)N_NODES * 128;         // 256*128
    _Float16* Wt2 = Wt1 + 256 * 128;                    // 256*128
    _Float16* Wt3 = Wt2 + 256 * 128;                    // 128*128
    int* deg  = (int*)(Wt3 + 128 * 128);                // 50000
    int* off  = deg + N_NODES;                          // 50001
    int* cur  = off + N_NODES + 1;                      // 50000
    int* csr  = cur + N_NODES;                          // 800000
    int* bsum = csr + N_EDGES;                          // SC_NB
    int* bbase= bsum + SC_NB;                           // SC_NB

    const int TB = 256;

    // ---- CSR build + precision prep ----
    hipMemsetAsync(deg, 0, (size_t)N_NODES * 4, stream);
    hist_deg<<<cdiv(N_EDGES, TB), TB, 0, stream>>>(edst, deg);
    cast_to_half<<<cdiv((long long)N_NODES * 32, TB), TB, 0, stream>>>(x, Xb, N_NODES * 32);
    pack_weights<<<cdiv(81920, TB), TB, 0, stream>>>(W1l, W1r, W2l, W2r, W3l, W3r, Wt1, Wt2, Wt3);
    scan_block_sums<<<SC_NB, SC_B, 0, stream>>>(deg, bsum);
    scan_bsum<<<1, 64, 0, stream>>>(bsum, bbase);
    scan_apply<<<SC_NB, SC_B, 0, stream>>>(deg, bbase, off, cur);
    scatter_csr<<<cdiv(N_EDGES, TB), TB, 0, stream>>>(esrc, edst, cur, csr);

    const int WPB = 4;
    int gat_grid = cdiv(N_NODES, WPB);
    dim3 g2(cdiv(N_NODES, 128), 2), g1(cdiv(N_NODES, 128), 1);

    // ---- layer 1 ----
    gemm_xlr<256><<<g2, 256, 0, stream>>>(Xb, Wt1, XLR);
    fused_gat<128, _Float16><<<gat_grid, WPB * 64, 0, stream>>>(XLR, off, csr, att1, b1, Hb);
    // ---- layer 2 ----
    gemm_xlr<256><<<g2, 256, 0, stream>>>(Hb, Wt2, XLR);
    fused_gat<128, _Float16><<<gat_grid, WPB * 64, 0, stream>>>(XLR, off, csr, att2, b2, Hb);
    // ---- layer 3 ----
    gemm_xlr<128><<<g1, 256, 0, stream>>>(Hb, Wt3, XLR);
    fused_gat<64, float><<<gat_grid, WPB * 64, 0, stream>>>(XLR, off, csr, att3, b3, out);
}

// Round 4
// 398.113 us; speedup vs baseline: 5.1961x; 1.0875x over previous
//
#include <hip/hip_runtime.h>
#include <hip/hip_fp16.h>
#include <math.h>

#define N_NODES 50000
#define N_EDGES 800000
#define NEG_SLOPE 0.2f

typedef _Float16 v8h __attribute__((ext_vector_type(8)));
typedef float f32x4 __attribute__((ext_vector_type(4)));

static inline int cdiv(long long a, int b) { return (int)((a + b - 1) / b); }

// ================= weight packing: W[K][N] f32 -> Wt[N][K] f16 =================
__global__ void pack_weights(const float* __restrict__ W1l, const float* __restrict__ W1r,
                             const float* __restrict__ W2l, const float* __restrict__ W2r,
                             const float* __restrict__ W3l, const float* __restrict__ W3r,
                             _Float16* __restrict__ Wt1, _Float16* __restrict__ Wt2,
                             _Float16* __restrict__ Wt3) {
    int id = blockIdx.x * blockDim.x + threadIdx.x;
    if (id < 32768) {                       // Wt1: [256][128]
        int n = id >> 7, k = id & 127;
        Wt1[id] = (_Float16)(n < 128 ? W1l[k * 128 + n] : W1r[k * 128 + n - 128]);
    } else if (id < 65536) {                // Wt2: [256][128]
        int j = id - 32768; int n = j >> 7, k = j & 127;
        Wt2[j] = (_Float16)(n < 128 ? W2l[k * 128 + n] : W2r[k * 128 + n - 128]);
    } else if (id < 81920) {                // Wt3: [128][128]
        int j = id - 65536; int n = j >> 7, k = j & 127;
        Wt3[j] = (_Float16)(n < 64 ? W3l[k * 64 + n] : W3r[k * 64 + n - 64]);
    }
}

// ================= CSR build =================
__global__ void hist_deg(const int* __restrict__ edst, int* __restrict__ deg) {
    int e = blockIdx.x * blockDim.x + threadIdx.x;
    if (e < N_EDGES) atomicAdd(&deg[edst[e]], 1);
}

#define SC_B 1024
#define SC_V 4
#define SC_CHUNK (SC_B * SC_V)                       // 4096
#define SC_NB ((N_NODES + SC_CHUNK - 1) / SC_CHUNK)  // 13

__global__ void scan_block_sums(const int* __restrict__ deg, int* __restrict__ bsum) {
    __shared__ int red[SC_B];
    int base = blockIdx.x * SC_CHUNK + threadIdx.x * SC_V;
    int s = 0;
#pragma unroll
    for (int u = 0; u < SC_V; ++u) {
        int i = base + u;
        if (i < N_NODES) s += deg[i];
    }
    red[threadIdx.x] = s;
    __syncthreads();
    for (int st = SC_B / 2; st > 0; st >>= 1) {
        if (threadIdx.x < st) red[threadIdx.x] += red[threadIdx.x + st];
        __syncthreads();
    }
    if (threadIdx.x == 0) bsum[blockIdx.x] = red[0];
}

// scan within chunk + inline cross-chunk base (13 blocks: serial prefix is trivial)
__global__ void scan_apply(const int* __restrict__ deg, const int* __restrict__ bsum,
                           int* __restrict__ off, int* __restrict__ cur) {
    __shared__ int buf[SC_B];
    __shared__ int s_base;
    if (threadIdx.x == 0) {
        int r = 0;
        for (int b = 0; b < blockIdx.x; ++b) r += bsum[b];
        s_base = r;
    }
    int idx0 = blockIdx.x * SC_CHUNK + threadIdx.x * SC_V;
    int v[SC_V];
    int sum = 0;
#pragma unroll
    for (int u = 0; u < SC_V; ++u) {
        int i = idx0 + u;
        v[u] = (i < N_NODES) ? deg[i] : 0;
        sum += v[u];
    }
    buf[threadIdx.x] = sum;
    __syncthreads();
    for (int st = 1; st < SC_B; st <<= 1) {
        int t = (threadIdx.x >= st) ? buf[threadIdx.x - st] : 0;
        __syncthreads();
        buf[threadIdx.x] += t;
        __syncthreads();
    }
    int run = s_base + buf[threadIdx.x] - sum;  // exclusive prefix
#pragma unroll
    for (int u = 0; u < SC_V; ++u) {
        int i = idx0 + u;
        if (i < N_NODES) { off[i] = run; cur[i] = run; }
        run += v[u];
    }
    if (blockIdx.x == 0 && threadIdx.x == 0) off[N_NODES] = N_EDGES;
}

__global__ void scatter_csr(const int* __restrict__ esrc, const int* __restrict__ edst,
                            int* __restrict__ cur, int* __restrict__ csr) {
    int e = blockIdx.x * blockDim.x + threadIdx.x;
    if (e < N_EDGES) {
        int d = edst[e];
        int p = atomicAdd(&cur[d], 1);
        csr[p] = esrc[e];
    }
}

// ===== MFMA GEMM: C[M][NT](f16) = A[M][128] @ Bt[NT][128]^T; A is f32 or f16 =====
template<int NT, typename AT>
__global__ __launch_bounds__(256, 2) void gemm_xlr(const AT* __restrict__ A,
                                                   const _Float16* __restrict__ Bt,
                                                   _Float16* __restrict__ C) {
    int w = threadIdx.x >> 6, lane = threadIdx.x & 63;
    int m0 = blockIdx.x * 128 + (w & 1) * 64;
    int n0 = blockIdx.y * 128 + (w >> 1) * 64;
    int q = lane >> 4, li = lane & 15;
    f32x4 acc[4][4] = {};
    const AT* Ap[4];
#pragma unroll
    for (int a = 0; a < 4; ++a) {
        int row = m0 + 16 * a + li;
        if (row > N_NODES - 1) row = N_NODES - 1;  // clamp: no OOB reads of input buffer
        Ap[a] = A + (size_t)row * 128 + q * 8;
    }
    const _Float16* Bp = Bt + (size_t)(n0 + li) * 128 + q * 8;
#pragma unroll
    for (int kt = 0; kt < 4; ++kt) {
        v8h af[4], bf[4];
#pragma unroll
        for (int a = 0; a < 4; ++a) {
            if constexpr (sizeof(AT) == 4) {
                float4 lo = *(const float4*)(Ap[a] + kt * 32);
                float4 hi = *(const float4*)(Ap[a] + kt * 32 + 4);
                v8h t;
                t[0] = (_Float16)lo.x; t[1] = (_Float16)lo.y; t[2] = (_Float16)lo.z; t[3] = (_Float16)lo.w;
                t[4] = (_Float16)hi.x; t[5] = (_Float16)hi.y; t[6] = (_Float16)hi.z; t[7] = (_Float16)hi.w;
                af[a] = t;
            } else {
                af[a] = *(const v8h*)(Ap[a] + kt * 32);
            }
        }
#pragma unroll
        for (int b = 0; b < 4; ++b) bf[b] = *(const v8h*)(Bp + (size_t)(16 * b) * 128 + kt * 32);
#pragma unroll
        for (int a = 0; a < 4; ++a)
#pragma unroll
            for (int b = 0; b < 4; ++b)
                acc[a][b] = __builtin_amdgcn_mfma_f32_16x16x32_f16(af[a], bf[b], acc[a][b], 0, 0, 0);
    }
    // C/D layout: col = lane&15, row = q*4 + reg
#pragma unroll
    for (int a = 0; a < 4; ++a) {
        int mb = m0 + 16 * a + q * 4;
#pragma unroll
        for (int r = 0; r < 4; ++r) {
            int m = mb + r;
            if (m < N_NODES) {
#pragma unroll
                for (int b = 0; b < 4; ++b) {
                    int n = n0 + 16 * b + li;
                    C[(size_t)m * NT + n] = (_Float16)acc[a][b][r];
                }
            }
        }
    }
}

// ================= fused GATv2: score + softmax (no max-sub) + aggregate + bias + elu ===========
// One wave per dst node; VEC=8 channels/lane (16B gathers), EPW edge-groups with depth-1 prefetch.
template<int HOUT, typename OUT_T>
__global__ __launch_bounds__(256, 4) void fused_gat(
    const _Float16* __restrict__ XLR,   // [N][2*HOUT] = [xl | xr]
    const int* __restrict__ off, const int* __restrict__ csr,
    const float* __restrict__ att, const float* __restrict__ bias,
    OUT_T* __restrict__ out) {          // [N][HOUT]
    constexpr int VEC = 8;
    constexpr int LPE = HOUT / VEC;     // lanes per edge (16 or 8)
    constexpr int EPW = 64 / LPE;       // edge groups per wave (4 or 8)
    constexpr int ST = 2 * HOUT;
    int wave = threadIdx.x >> 6, lane = threadIdx.x & 63;
    int node = blockIdx.x * (blockDim.x >> 6) + wave;
    if (node >= N_NODES) return;
    int g = lane / LPE;
    int lg = lane % LPE;
    int cb = lg * VEC;

    float at[VEC], xr[VEC];
#pragma unroll
    for (int u = 0; u < VEC; ++u) at[u] = att[cb + u];
    v8h xrh = *(const v8h*)(XLR + (size_t)node * ST + HOUT + cb);
#pragma unroll
    for (int u = 0; u < VEC; ++u) xr[u] = (float)xrh[u];

    int eoff = off[node];
    int P = off[node + 1] - eoff + 1;   // position 0 = self-loop, 1..deg = csr edges
    float denom = 0.f, acc[VEC];
#pragma unroll
    for (int u = 0; u < VEC; ++u) acc[u] = 0.f;

    int p = g;
    v8h ah;
    if (p < P) {
        int src = (p == 0) ? node : csr[eoff + p - 1];
        ah = *(const v8h*)(XLR + (size_t)src * ST + cb);
    }
    while (p < P) {
        v8h ch = ah;
        int pn = p + EPW;
        if (pn < P) {                       // pn >= EPW > 0, never the self-loop
            int srcn = csr[eoff + pn - 1];
            ah = *(const v8h*)(XLR + (size_t)srcn * ST + cb);
        }
        float a[VEC];
#pragma unroll
        for (int u = 0; u < VEC; ++u) a[u] = (float)ch[u];
        float s = 0.f;
#pragma unroll
        for (int u = 0; u < VEC; ++u) {
            float v = a[u] + xr[u];
            s += at[u] * fmaxf(v, NEG_SLOPE * v);  // leaky_relu
        }
        // per-head reduce: C=64, VEC=8 -> 8 lanes per head, head groups are 8-aligned
        s += __shfl_xor(s, 1); s += __shfl_xor(s, 2); s += __shfl_xor(s, 4);
        float f = __expf(s);
        denom += f;
#pragma unroll
        for (int u = 0; u < VEC; ++u) acc[u] += a[u] * f;
        p = pn;
    }
    // merge the EPW edge groups (lg stays fixed under these xors)
#pragma unroll
    for (int o = LPE; o < 64; o <<= 1) {
#pragma unroll
        for (int u = 0; u < VEC; ++u) acc[u] += __shfl_xor(acc[u], o);
        denom += __shfl_xor(denom, o);
    }
    if (lane < LPE) {
        float inv = 1.f / denom;
        OUT_T* orow = out + (size_t)node * HOUT + cb;
#pragma unroll
        for (int u = 0; u < VEC; ++u) {
            float r = acc[u] * inv + bias[cb + u];
            r = r > 0.f ? r : expm1f(r);
            orow[u] = (OUT_T)r;
        }
    }
}

extern "C" void kernel_launch(void* const* d_in, const int* in_sizes, int n_in,
                              void* d_out, int out_size, void* d_ws, size_t ws_size,
                              hipStream_t stream) {
    const float* x    = (const float*)d_in[0];
    const int*   ei   = (const int*)d_in[1];
    const int*   esrc = ei;
    const int*   edst = ei + N_EDGES;
    const float* W1l = (const float*)d_in[2];
    const float* W1r = (const float*)d_in[3];
    const float* att1= (const float*)d_in[4];
    const float* b1  = (const float*)d_in[5];
    const float* W2l = (const float*)d_in[6];
    const float* W2r = (const float*)d_in[7];
    const float* att2= (const float*)d_in[8];
    const float* b2  = (const float*)d_in[9];
    const float* W3l = (const float*)d_in[10];
    const float* W3r = (const float*)d_in[11];
    const float* att3= (const float*)d_in[12];
    const float* b3  = (const float*)d_in[13];
    float* out = (float*)d_out;

    // ---- workspace layout ----
    _Float16* XLR = (_Float16*)d_ws;                    // 50000*256
    _Float16* Hb  = XLR + (size_t)N_NODES * 256;        // 50000*128
    _Float16* Wt1 = Hb + (size_t)N_NODES * 128;         // 256*128
    _Float16* Wt2 = Wt1 + 256 * 128;                    // 256*128
    _Float16* Wt3 = Wt2 + 256 * 128;                    // 128*128
    int* deg  = (int*)(Wt3 + 128 * 128);                // 50000
    int* off  = deg + N_NODES;                          // 50001
    int* cur  = off + N_NODES + 1;                      // 50000
    int* csr  = cur + N_NODES;                          // 800000
    int* bsum = csr + N_EDGES;                          // SC_NB

    const int TB = 256;

    // ---- CSR build + weight prep ----
    hipMemsetAsync(deg, 0, (size_t)N_NODES * 4, stream);
    hist_deg<<<cdiv(N_EDGES, TB), TB, 0, stream>>>(edst, deg);
    pack_weights<<<cdiv(81920, TB), TB, 0, stream>>>(W1l, W1r, W2l, W2r, W3l, W3r, Wt1, Wt2, Wt3);
    scan_block_sums<<<SC_NB, SC_B, 0, stream>>>(deg, bsum);
    scan_apply<<<SC_NB, SC_B, 0, stream>>>(deg, bsum, off, cur);
    scatter_csr<<<cdiv(N_EDGES, TB), TB, 0, stream>>>(esrc, edst, cur, csr);

    const int WPB = 4;
    int gat_grid = cdiv(N_NODES, WPB);
    dim3 g2(cdiv(N_NODES, 128), 2), g1(cdiv(N_NODES, 128), 1);

    // ---- layer 1 (A = f32 input; cast fused into GEMM) ----
    gemm_xlr<256, float><<<g2, 256, 0, stream>>>(x, Wt1, XLR);
    fused_gat<128, _Float16><<<gat_grid, WPB * 64, 0, stream>>>(XLR, off, csr, att1, b1, Hb);
    // ---- layer 2 ----
    gemm_xlr<256, _Float16><<<g2, 256, 0, stream>>>(Hb, Wt2, XLR);
    fused_gat<128, _Float16><<<gat_grid, WPB * 64, 0, stream>>>(XLR, off, csr, att2, b2, Hb);
    // ---- layer 3 ----
    gemm_xlr<128, _Float16><<<g1, 256, 0, stream>>>(Hb, Wt3, XLR);
    fused_gat<64, float><<<gat_grid, WPB * 64, 0, stream>>>(XLR, off, csr, att3, b3, out);
}